// Round 3
// baseline (719.817 us; speedup 1.0000x reference)
//
#include <hip/hip_runtime.h>

// Problem constants (from reference)
#define NE    8
#define KDIM  2048
#define NDIM  5632
#define NTOK  4096
#define CAP   512      // tokens per expert (balanced routing, = NTOK/NE)
#define NGRP  32       // KDIM / GROUP_SIZE(64)
#define BM    128
#define BN    128
#define BK    32
#define MT    4        // CAP / BM
#define NT    44       // NDIM / BN

#define NBT   44                                   // NDIM / 128 (transpose n-blocks)
#define TRB   (NE * NGRP * NBT)                    // 11264 transpose blocks
#define ACV_BLOCKS  (NTOK * KDIM / (8 * 256))      // 4096 A-convert blocks
#define PS    134                                  // LDS transpose row stride (elems)

#define WT_BYTES  ((size_t)NE * KDIM * NDIM * 2)   // 184,549,376 bf16 transposed W
#define ABF_BYTES ((size_t)NTOK * KDIM * 2)        // 16,777,216 bf16 A

typedef __attribute__((ext_vector_type(8))) short bf16x8;
typedef __attribute__((ext_vector_type(4))) short bf16x4;
typedef __attribute__((ext_vector_type(4))) float f32x4;

typedef __attribute__((address_space(3))) unsigned int* lds_p;
typedef const __attribute__((address_space(1))) unsigned int* glb_p;

static __device__ __forceinline__ void ld16(const void* g, void* l) {
    __builtin_amdgcn_global_load_lds((glb_p)g, (lds_p)l, 16, 0, 0);
}

// fp32 -> bf16 round-to-nearest-even (finite inputs only)
static __device__ __forceinline__ unsigned short f2bf(float f) {
    union { float f; unsigned u; } x; x.f = f;
    return (unsigned short)((x.u + 0x7fffu + ((x.u >> 16) & 1u)) >> 16);
}

// ---------------- Pass 1: dequant W -> bf16 transposed [e][n][k]; A -> bf16 ----
__global__ __launch_bounds__(256)
void prep_kernel(const int* __restrict__ wq, const float* __restrict__ inp,
                 const float* __restrict__ sz,
                 unsigned short* __restrict__ wt, unsigned short* __restrict__ abf)
{
    const int bid = blockIdx.x;
    if (bid < TRB) {
        // one block: 64 k (one quant group g) x 128 n, dequant + transpose
        const int e  = bid / (NGRP * NBT);
        const int r  = bid % (NGRP * NBT);
        const int g  = r / NBT;
        const int nb = r % NBT;
        __shared__ unsigned short T[64 * PS];   // [k][n], stride PS
        const int t = threadIdx.x;

        // phase 1: coalesced int4 reads along n, dequant, LDS [k][n]
        const int n4    = (t & 31) * 4;
        const int r0    = t >> 5;                  // 0..7
        const int nglob = nb * 128 + n4;
        const float* szp = sz + ((size_t)(e * NGRP + g) * NDIM + nglob) * 2;
        const float4 sz01 = *(const float4*)szp;        // s0 z0 s1 z1
        const float4 sz23 = *(const float4*)(szp + 4);  // s2 z2 s3 z3
        const float s0 = sz01.x, z0 = sz01.y - 8.f * sz01.x;
        const float s1 = sz01.z, z1 = sz01.w - 8.f * sz01.z;
        const float s2 = sz23.x, z2 = sz23.y - 8.f * sz23.x;
        const float s3 = sz23.z, z3 = sz23.w - 8.f * sz23.z;
        const int* cbase = wq + (size_t)(e * KDIM + g * 64) * NDIM + nglob;
        #pragma unroll
        for (int ri = 0; ri < 8; ++ri) {
            const int row = r0 + ri * 8;
            const int4 c = *(const int4*)(cbase + (size_t)row * NDIM);
            unsigned p0 = (unsigned)f2bf(fmaf((float)c.x, s0, z0))
                        | ((unsigned)f2bf(fmaf((float)c.y, s1, z1)) << 16);
            unsigned p1 = (unsigned)f2bf(fmaf((float)c.z, s2, z2))
                        | ((unsigned)f2bf(fmaf((float)c.w, s3, z3)) << 16);
            unsigned* dst = (unsigned*)&T[row * PS + n4];
            dst[0] = p0; dst[1] = p1;
        }
        __syncthreads();

        // phase 2: transposed reads, coalesced 16B/lane stores (8 lanes per n-row)
        const int kq = t & 7;
        #pragma unroll
        for (int it = 0; it < 4; ++it) {
            const int n = it * 32 + (t >> 3);
            bf16x8 v;
            #pragma unroll
            for (int i = 0; i < 8; ++i)
                v[i] = (short)T[(kq * 8 + i) * PS + n];
            unsigned short* dp = wt + ((size_t)e * NDIM + nb * 128 + n) * KDIM
                                    + g * 64 + kq * 8;
            *(bf16x8*)dp = v;
        }
    } else {
        // A fp32 -> bf16, 8 elems/thread
        const size_t t = (size_t)(bid - TRB) * 256 + threadIdx.x;
        const float4* p = (const float4*)inp + t * 2;
        const float4 v0 = p[0], v1 = p[1];
        bf16x8 h;
        h[0] = (short)f2bf(v0.x); h[1] = (short)f2bf(v0.y);
        h[2] = (short)f2bf(v0.z); h[3] = (short)f2bf(v0.w);
        h[4] = (short)f2bf(v1.x); h[5] = (short)f2bf(v1.y);
        h[6] = (short)f2bf(v1.z); h[7] = (short)f2bf(v1.w);
        *((bf16x8*)abf + t) = h;
    }
}

// ---------------- Pass 2: m97-structure bf16 GEMM (global_load_lds both sides) ----
__global__ __launch_bounds__(256)
void hqq_gemm3(const unsigned short* __restrict__ abf,
               const unsigned short* __restrict__ wt,
               float* __restrict__ out)
{
    const int bid = blockIdx.x;
    const int e   = bid / (MT * NT);
    const int rem = bid % (MT * NT);
    const int nt  = rem >> 2;
    const int mt  = rem & 3;

    __shared__ __align__(16) unsigned short Alds[BM * BK];  // [m][k], 64B rows, unpadded
    __shared__ __align__(16) unsigned short Blds[BN * BK];  // [n][k]

    const int tid  = threadIdx.x;
    const int wave = tid >> 6;
    const int lane = tid & 63;
    const int m0   = e * CAP + mt * BM;
    const int n0   = nt * BN;

    // staging: wave w covers rows [32w, 32w+32) in two 16-row chunks;
    // lane -> (row = base + (lane>>2), k-octet = lane&3); LDS dest = chunkbase + 16*lane
    const int srow = wave * 32 + (lane >> 2);
    const int skq  = lane & 3;
    const unsigned short* Ag0 = abf + (size_t)(m0 + srow) * KDIM + skq * 8;
    const unsigned short* Ag1 = Ag0 + (size_t)16 * KDIM;
    const unsigned short* Bg0 = wt + ((size_t)e * NDIM + n0 + srow) * KDIM + skq * 8;
    const unsigned short* Bg1 = Bg0 + (size_t)16 * KDIM;
    unsigned short* Al0 = &Alds[wave * 1024];
    unsigned short* Al1 = &Alds[wave * 1024 + 512];
    unsigned short* Bl0 = &Blds[wave * 1024];
    unsigned short* Bl1 = &Blds[wave * 1024 + 512];

    f32x4 acc[4][4];
    #pragma unroll
    for (int i = 0; i < 4; ++i)
        #pragma unroll
        for (int j = 0; j < 4; ++j)
            acc[i][j] = (f32x4){0.f, 0.f, 0.f, 0.f};

    const int wm = (wave >> 1) << 6;
    const int wn = (wave & 1) << 6;
    const int lr = lane & 15;
    const int lq = lane >> 4;

    for (int kk = 0; kk < KDIM / BK; ++kk) {
        ld16(Ag0, Al0);
        ld16(Ag1, Al1);
        ld16(Bg0, Bl0);
        ld16(Bg1, Bl1);
        Ag0 += BK; Ag1 += BK; Bg0 += BK; Bg1 += BK;
        __syncthreads();

        bf16x8 af[4], bfv[4];
        #pragma unroll
        for (int i = 0; i < 4; ++i)
            af[i] = *(const bf16x8*)&Alds[(wm + i * 16 + lr) * BK + lq * 8];
        #pragma unroll
        for (int j = 0; j < 4; ++j)
            bfv[j] = *(const bf16x8*)&Blds[(wn + j * 16 + lr) * BK + lq * 8];
        #pragma unroll
        for (int i = 0; i < 4; ++i)
            #pragma unroll
            for (int j = 0; j < 4; ++j)
                acc[i][j] = __builtin_amdgcn_mfma_f32_16x16x32_bf16(af[i], bfv[j], acc[i][j], 0, 0, 0);

        __syncthreads();
    }

    // epilogue: C/D layout row=(lane>>4)*4+reg, col=lane&15
    const int orow0 = m0 + wm + lq * 4;
    const int ocol0 = n0 + wn + lr;
    #pragma unroll
    for (int i = 0; i < 4; ++i)
        #pragma unroll
        for (int r = 0; r < 4; ++r) {
            float* op = out + (size_t)(orow0 + i * 16 + r) * NDIM + ocol0;
            #pragma unroll
            for (int j = 0; j < 4; ++j)
                op[j * 16] = acc[i][j][r];
        }
}

// ---------------- Fallback (R2 fused kernel) if ws too small ----------------
#define LDSS  40
__global__ __launch_bounds__(256, 2)
void hqq_gemm_fallback(const float* __restrict__ inp,
                       const int*   __restrict__ wq,
                       const float* __restrict__ sz,
                       float*       __restrict__ out)
{
    const int bid = blockIdx.x;
    const int e   = bid / (MT * NT);
    const int rem = bid % (MT * NT);
    const int nt  = rem >> 2;
    const int mt  = rem & 3;

    __shared__ __align__(16) short Alds[BM * LDSS];
    __shared__ __align__(16) short Blds[BN * LDSS];

    const int tid = threadIdx.x;
    const int m0  = e * CAP + mt * BM;
    const int n0  = nt * BN;

    const int a_kq  = tid & 7;
    const int a_row = tid >> 3;
    const int b_n   = tid & 127;
    const int b_h   = tid >> 7;

    const float* Ab  = inp + (size_t)m0 * KDIM;
    const int*   Wb  = wq  + (size_t)e * KDIM * NDIM + n0 + b_n;
    const float* SZb = sz  + (size_t)e * NGRP * (NDIM * 2) + (size_t)(n0 + b_n) * 2;

    f32x4 acc[4][4];
    #pragma unroll
    for (int i = 0; i < 4; ++i)
        #pragma unroll
        for (int j = 0; j < 4; ++j)
            acc[i][j] = (f32x4){0.f, 0.f, 0.f, 0.f};

    const int wave = tid >> 6;
    const int lane = tid & 63;
    const int wm = (wave >> 1) << 6;
    const int wn = (wave & 1) << 6;
    const int lr = lane & 15;
    const int lq = lane >> 4;

    for (int k0 = 0; k0 < KDIM; k0 += BK) {
        const int g = k0 >> 6;
        #pragma unroll
        for (int p = 0; p < 4; ++p) {
            const int row = a_row + p * 32;
            const float4 v = *(const float4*)(Ab + (size_t)row * KDIM + k0 + a_kq * 4);
            bf16x4 h;
            h[0] = (short)f2bf(v.x); h[1] = (short)f2bf(v.y);
            h[2] = (short)f2bf(v.z); h[3] = (short)f2bf(v.w);
            *(bf16x4*)&Alds[row * LDSS + a_kq * 4] = h;
        }
        const float2 s2 = *(const float2*)(SZb + (size_t)g * (NDIM * 2));
        const float s  = s2.x;
        const float z8 = s2.y - 8.f * s2.x;
        #pragma unroll
        for (int oo = 0; oo < 2; ++oo) {
            const int ko = b_h * 8 + oo * 16;
            const int* wp = Wb + (size_t)(k0 + ko) * NDIM;
            bf16x8 bb;
            #pragma unroll
            for (int j = 0; j < 8; ++j) {
                const float q = (float)wp[(size_t)j * NDIM];
                bb[j] = (short)f2bf(fmaf(q, s, z8));
            }
            *(bf16x8*)&Blds[b_n * LDSS + ko] = bb;
        }
        __syncthreads();
        bf16x8 af[4], bfv[4];
        #pragma unroll
        for (int i = 0; i < 4; ++i)
            af[i] = *(const bf16x8*)&Alds[(wm + i * 16 + lr) * LDSS + lq * 8];
        #pragma unroll
        for (int j = 0; j < 4; ++j)
            bfv[j] = *(const bf16x8*)&Blds[(wn + j * 16 + lr) * LDSS + lq * 8];
        #pragma unroll
        for (int i = 0; i < 4; ++i)
            #pragma unroll
            for (int j = 0; j < 4; ++j)
                acc[i][j] = __builtin_amdgcn_mfma_f32_16x16x32_bf16(af[i], bfv[j], acc[i][j], 0, 0, 0);
        __syncthreads();
    }

    const int orow0 = m0 + wm + lq * 4;
    const int ocol0 = n0 + wn + lr;
    #pragma unroll
    for (int i = 0; i < 4; ++i)
        #pragma unroll
        for (int r = 0; r < 4; ++r) {
            float* op = out + (size_t)(orow0 + i * 16 + r) * NDIM + ocol0;
            #pragma unroll
            for (int j = 0; j < 4; ++j)
                op[j * 16] = acc[i][j][r];
        }
}

extern "C" void kernel_launch(void* const* d_in, const int* in_sizes, int n_in,
                              void* d_out, int out_size, void* d_ws, size_t ws_size,
                              hipStream_t stream) {
    const float* inp = (const float*)d_in[0];
    const int*   wq  = (const int*)d_in[2];
    const float* sz  = (const float*)d_in[3];
    float*       out = (float*)d_out;

    if (ws_size >= WT_BYTES + ABF_BYTES) {
        unsigned short* wt  = (unsigned short*)d_ws;
        unsigned short* abf = (unsigned short*)((char*)d_ws + WT_BYTES);
        prep_kernel<<<dim3(TRB + ACV_BLOCKS), dim3(256), 0, stream>>>(wq, inp, sz, wt, abf);
        hqq_gemm3<<<dim3(NE * MT * NT), dim3(256), 0, stream>>>(abf, wt, out);
    } else {
        hqq_gemm_fallback<<<dim3(NE * MT * NT), dim3(256), 0, stream>>>(inp, wq, sz, out);
    }
}